// Round 1
// baseline (1043.354 us; speedup 1.0000x reference)
//
#include <hip/hip_runtime.h>

// Problem constants
#define Bdim 2048
#define Sdim 32
#define Ddim 1024
#define Fdim 512
#define Hdim 512

typedef __bf16 bf16_t;
typedef __bf16 bf16x8 __attribute__((ext_vector_type(8)));
typedef __bf16 bf16x4 __attribute__((ext_vector_type(4)));
typedef float  f32x4  __attribute__((ext_vector_type(4)));

#define BM 128
#define BN 128
#define BK 32

// ---------------- async global->LDS, 16B per lane ----------------
__device__ __forceinline__ void gll16(const bf16_t* g, bf16_t* l) {
  __builtin_amdgcn_global_load_lds((const __attribute__((address_space(1))) void*)g,
                                   (__attribute__((address_space(3))) void*)l,
                                   16, 0, 0);
}

// XOR-swizzled LDS offset for BK=32 tiles: slot (row, k-chunk c) holds global chunk
// c ^ ((row>>1)&3). Staging stays lane-contiguous (global_load_lds compatible) and
// fully coalesced; fragment reads spread across all 8 bank groups (2-way = free).
__device__ __forceinline__ int swz32(int row, int k) {
  return row * 32 + (((((k >> 3) ^ ((row >> 1) & 3))) << 3) | (k & 7));
}

// ---------------- fused fp32 -> bf16 convert for ALL weight/input tensors ----------------
__global__ void k_cvt_all(const float* __restrict__ q, const float* __restrict__ ipw,
                          const float* __restrict__ ow, const float* __restrict__ cw1,
                          const float* __restrict__ fusw, const float* __restrict__ paw,
                          const float* __restrict__ pvw,
                          bf16_t* __restrict__ q16, bf16_t* __restrict__ w16,
                          bf16_t* __restrict__ ow16, bf16_t* __restrict__ cls16,
                          bf16_t* __restrict__ hw16) {
  long v = (long)blockIdx.x * 256 + threadIdx.x;
  const float* s; bf16_t* d; long off;
  if (v < 16777216L)      { s = q;    d = q16;            off = 0; }
  else if (v < 17563648L) { s = ipw;  d = w16;            off = 16777216L; }
  else if (v < 17825792L) { s = ow;   d = ow16;           off = 17563648L; }
  else if (v < 22020096L) { s = cw1;  d = cls16;          off = 17825792L; }
  else if (v < 22151168L) { s = fusw; d = hw16;           off = 22020096L; }
  else if (v < 22282240L) { s = paw;  d = hw16 + 524288;  off = 22151168L; }
  else                    { s = pvw;  d = hw16 + 1048576; off = 22282240L; }
  long i = (v - off) * 4;
  float4 t = *(const float4*)(s + i);
  bf16x4 o;
  o[0] = (bf16_t)t.x; o[1] = (bf16_t)t.y; o[2] = (bf16_t)t.z; o[3] = (bf16_t)t.w;
  *(bf16x4*)(d + i) = o;
}

// ---------------- bias precompute: u = Wq^T bk, w = Wk^T bq, b' = Wo bv + out_b, c0 = bq.bk
__global__ void k_bias_pre(const float* __restrict__ ipw, const float* __restrict__ ipb,
                           const float* __restrict__ ow, const float* __restrict__ ob,
                           float* __restrict__ u, float* __restrict__ w,
                           float* __restrict__ bp, float* __restrict__ c0) {
  int blk = blockIdx.x, tid = threadIdx.x;
  if (blk < 4) {
    int d = blk * 256 + tid;
    float acc = 0.f;
    #pragma unroll 8
    for (int e = 0; e < Ddim; ++e) acc += ipw[(long)e * Ddim + d] * ipb[Ddim + e];
    u[d] = acc;
  } else if (blk < 8) {
    int d = (blk - 4) * 256 + tid;
    float acc = 0.f;
    #pragma unroll 8
    for (int e = 0; e < Ddim; ++e) acc += ipw[(long)(Ddim + e) * Ddim + d] * ipb[e];
    w[d] = acc;
  } else if (blk < 136) {
    int o = (blk - 8) * 8 + (tid >> 5);
    int l = tid & 31;
    float acc = 0.f;
    #pragma unroll 4
    for (int e = l; e < Ddim; e += 32) acc += ow[(long)o * Ddim + e] * ipb[2 * Ddim + e];
    #pragma unroll
    for (int m = 1; m < 32; m <<= 1) acc += __shfl_xor(acc, m);
    if (l == 0) bp[o] = acc + ob[o];
  } else {
    __shared__ float red[256];
    float acc = 0.f;
    for (int e = tid; e < Ddim; e += 256) acc += ipb[e] * ipb[Ddim + e];
    red[tid] = acc;
    __syncthreads();
    for (int off = 128; off; off >>= 1) {
      if (tid < off) red[tid] += red[tid + off];
      __syncthreads();
    }
    if (tid == 0) c0[0] = red[0];
  }
}

// ---------------- generic 128x128x32 MFMA mainloop (operand-swapped mfma, swizzled LDS) --
// acc[i][j][r] = C[m0+wm+i*16+l16][n0+wn+j*16+quad*4+r]
template<int AT, int BT>
__device__ __forceinline__ void gemm_tile(const bf16_t* __restrict__ A, long lda,
                                          const bf16_t* __restrict__ Bt, long ldb,
                                          long m0, long n0, int K,
                                          bf16_t* sa, bf16_t* sb, f32x4 acc[4][4]) {
  const int tid  = threadIdx.x;
  const int wave = tid >> 6;
  const int lane = tid & 63;
  const int quad = lane >> 4;
  const int l16  = lane & 15;
  const int wm = (wave & 1) * 64;
  const int wn = (wave >> 1) * 64;

  for (int kt = 0; kt < K; kt += BK) {
    __syncthreads();
    if constexpr (AT == 0) {
      #pragma unroll
      for (int r = 0; r < 2; ++r) {
        int L = r * 256 + tid;
        int row = L >> 2, cs = L & 3;
        int csrc = cs ^ ((row >> 1) & 3);
        gll16(A + (m0 + row) * lda + kt + csrc * 8, sa + (long)(r * 256 + wave * 64) * 8);
      }
    } else {
      #pragma unroll
      for (int r = 0; r < 2; ++r) {
        int L = r * 256 + tid;
        int gk = L >> 4, gm = (L & 15) * 8;
        bf16x8 v = *(const bf16x8*)(A + (long)(kt + gk) * lda + m0 + gm);
        #pragma unroll
        for (int j = 0; j < 8; ++j) sa[swz32(gm + j, gk)] = v[j];
      }
    }
    if constexpr (BT == 0) {
      #pragma unroll
      for (int r = 0; r < 2; ++r) {
        int L = r * 256 + tid;
        int row = L >> 2, cs = L & 3;
        int csrc = cs ^ ((row >> 1) & 3);
        gll16(Bt + (n0 + row) * ldb + kt + csrc * 8, sb + (long)(r * 256 + wave * 64) * 8);
      }
    } else {
      #pragma unroll
      for (int r = 0; r < 2; ++r) {
        int L = r * 256 + tid;
        int gk = L >> 4, gn = (L & 15) * 8;
        bf16x8 v = *(const bf16x8*)(Bt + (long)(kt + gk) * ldb + n0 + gn);
        #pragma unroll
        for (int j = 0; j < 8; ++j) sb[swz32(gn + j, gk)] = v[j];
      }
    }
    __syncthreads();
    bf16x8 af[4], bfr[4];
    #pragma unroll
    for (int i = 0; i < 4; ++i) {
      int row = wm + i * 16 + l16;
      af[i] = *(const bf16x8*)(sa + row * 32 + ((quad ^ ((row >> 1) & 3)) << 3));
    }
    #pragma unroll
    for (int j = 0; j < 4; ++j) {
      int row = wn + j * 16 + l16;
      bfr[j] = *(const bf16x8*)(sb + row * 32 + ((quad ^ ((row >> 1) & 3)) << 3));
    }
    #pragma unroll
    for (int i = 0; i < 4; ++i)
      #pragma unroll
      for (int j = 0; j < 4; ++j)
        acc[i][j] = __builtin_amdgcn_mfma_f32_16x16x32_bf16(bfr[j], af[i], acc[i][j], 0, 0, 0);
  }
}

// ---------------- GEMM with bf16 output (+optional fp32 bias on n), vectorized stores ----
template<int AT, int BT>
__global__ __launch_bounds__(256) void k_gemm_bf16(
    const bf16_t* __restrict__ A, long lda, long sAz,
    const bf16_t* __restrict__ Bt, long ldb, long sBz,
    bf16_t* __restrict__ C, long ldc, long sCz,
    const float* __restrict__ bias, int K) {
  __shared__ bf16_t sa[BM * BK];
  __shared__ bf16_t sb[BN * BK];
  long n0 = (long)blockIdx.x * BN;
  long m0 = (long)blockIdx.y * BM;
  long z  = blockIdx.z;
  const bf16_t* Az = A + z * sAz;
  const bf16_t* Bz = Bt + z * sBz;
  bf16_t* Cz = C + z * sCz;
  f32x4 acc[4][4];
  #pragma unroll
  for (int i = 0; i < 4; ++i)
    #pragma unroll
    for (int j = 0; j < 4; ++j) acc[i][j] = (f32x4){0.f, 0.f, 0.f, 0.f};
  gemm_tile<AT, BT>(Az, lda, Bz, ldb, m0, n0, K, sa, sb, acc);
  const int tid = threadIdx.x, wave = tid >> 6, lane = tid & 63;
  const int quad = lane >> 4, l16 = lane & 15;
  const int wm = (wave & 1) * 64, wn = (wave >> 1) * 64;
  #pragma unroll
  for (int i = 0; i < 4; ++i) {
    long row = m0 + wm + i * 16 + l16;
    #pragma unroll
    for (int j = 0; j < 4; ++j) {
      long col = n0 + wn + j * 16 + quad * 4;
      f32x4 b4 = bias ? *(const f32x4*)(bias + col) : (f32x4){0.f, 0.f, 0.f, 0.f};
      bf16x4 o;
      #pragma unroll
      for (int r = 0; r < 4; ++r) o[r] = (bf16_t)(acc[i][j][r] + b4[r]);
      *(bf16x4*)(Cz + row * ldc + col) = o;
    }
  }
}

// ---------------- GEMM with fp32 output (heads), vectorized f32x4 stores ----------------
__global__ __launch_bounds__(256) void k_gemm_f32(
    const bf16_t* __restrict__ A, long lda, long sAz,
    const bf16_t* __restrict__ Bt, long ldb, long sBz,
    float* __restrict__ C, long ldc, long sCz, int K) {
  __shared__ bf16_t sa[BM * BK];
  __shared__ bf16_t sb[BN * BK];
  long n0 = (long)blockIdx.x * BN;
  long m0 = (long)blockIdx.y * BM;
  long z  = blockIdx.z;
  const bf16_t* Az = A + z * sAz;
  const bf16_t* Bz = Bt + z * sBz;
  float* Cz = C + z * sCz;
  f32x4 acc[4][4];
  #pragma unroll
  for (int i = 0; i < 4; ++i)
    #pragma unroll
    for (int j = 0; j < 4; ++j) acc[i][j] = (f32x4){0.f, 0.f, 0.f, 0.f};
  gemm_tile<0, 0>(Az, lda, Bz, ldb, m0, n0, K, sa, sb, acc);
  const int tid = threadIdx.x, wave = tid >> 6, lane = tid & 63;
  const int quad = lane >> 4, l16 = lane & 15;
  const int wm = (wave & 1) * 64, wn = (wave >> 1) * 64;
  #pragma unroll
  for (int i = 0; i < 4; ++i) {
    long row = m0 + wm + i * 16 + l16;
    #pragma unroll
    for (int j = 0; j < 4; ++j) {
      long col = n0 + wn + j * 16 + quad * 4;
      *(f32x4*)(Cz + row * ldc + col) = acc[i][j];
    }
  }
}

// ---------------- big-tile GEMM for G = q16 @ M : 256x256 block, BK=32 -------------------
// T3+T4 pipelined: triple-buffered LDS (96 KB), prefetch distance 2 K-tiles, ONE raw
// s_barrier + ONE counted s_waitcnt vmcnt(4) per K-tile (never drains to 0 in the loop).
// Correctness of the single barrier: at iter t every wave has (a) finished reading
// buf[t-1] (its compute of tile t-1 preceded the barrier) and (b) waited vmcnt(4), i.e.
// its own 4 loads for tile t retired; the barrier makes both global. STAGE(t+2) targets
// buf[(t+2)%3] == buf[(t-1)%3], written only after that barrier. T5 setprio around MFMA.
__global__ __launch_bounds__(512, 2) void k_gemm_big(
    const bf16_t* __restrict__ A, const bf16_t* __restrict__ Bt,
    bf16_t* __restrict__ C) {
  __shared__ bf16_t sa[3][256 * 32];   // 3 x 16 KB
  __shared__ bf16_t sb[3][256 * 32];   // 3 x 16 KB
  const int tid = threadIdx.x, wave = tid >> 6, lane = tid & 63;
  const int quad = lane >> 4, l16 = lane & 15;
  // grid 1024 blocks; bijective XCD swizzle (1024 % 8 == 0), n-inner for A-panel L2 reuse
  int lin = blockIdx.x;
  int c = lin & 7, t0 = lin >> 3;
  int wg = c * 128 + t0;
  long m0 = (long)(wg >> 2) * 256;
  long n0 = (long)(wg & 3) * 256;
  const int wm = (wave >> 2) * 128;     // 2 waves in M
  const int wn = (wave & 3) * 64;       // 4 waves in N
  // staging: thread covers rows rowS and rowS+128 (one 16B chunk each, XOR swizzled)
  const int rowS = tid >> 2, cs = tid & 3;
  const int csrcS = cs ^ ((rowS >> 1) & 3);   // same for row and row+128 (128 ≡ 0 mod 4)
  const bf16_t* Abase = A + (m0 + rowS) * 1024 + csrcS * 8;
  const bf16_t* Bbase = Bt + (n0 + rowS) * 1024 + csrcS * 8;
  const int dst0 = wave * 512;          // elements; lane l writes dst0 + l*8
  const int dst1 = 4096 + wave * 512;

  f32x4 acc[8][4];
  #pragma unroll
  for (int i = 0; i < 8; ++i)
    #pragma unroll
    for (int j = 0; j < 4; ++j) acc[i][j] = (f32x4){0.f, 0.f, 0.f, 0.f};

#define GB_STAGE(KT, BUF)                                    \
  do {                                                       \
    const bf16_t* Ab = Abase + (KT);                         \
    const bf16_t* Bb = Bbase + (KT);                         \
    gll16(Ab,              sa[BUF] + dst0);                  \
    gll16(Ab + 128 * 1024, sa[BUF] + dst1);                  \
    gll16(Bb,              sb[BUF] + dst0);                  \
    gll16(Bb + 128 * 1024, sb[BUF] + dst1);                  \
  } while (0)

#define GB_COMPUTE(BUF)                                                            \
  do {                                                                             \
    bf16x8 af[8], bfr[4];                                                          \
    _Pragma("unroll")                                                              \
    for (int i = 0; i < 8; ++i) {                                                  \
      int row = wm + i * 16 + l16;                                                 \
      af[i] = *(const bf16x8*)(&sa[BUF][row * 32 + ((quad ^ ((row >> 1) & 3)) << 3)]); \
    }                                                                              \
    _Pragma("unroll")                                                              \
    for (int j = 0; j < 4; ++j) {                                                  \
      int row = wn + j * 16 + l16;                                                 \
      bfr[j] = *(const bf16x8*)(&sb[BUF][row * 32 + ((quad ^ ((row >> 1) & 3)) << 3)]); \
    }                                                                              \
    __builtin_amdgcn_s_setprio(1);                                                 \
    _Pragma("unroll")                                                              \
    for (int i = 0; i < 8; ++i)                                                    \
      _Pragma("unroll")                                                            \
      for (int j = 0; j < 4; ++j)                                                  \
        acc[i][j] = __builtin_amdgcn_mfma_f32_16x16x32_bf16(bfr[j], af[i], acc[i][j], 0, 0, 0); \
    __builtin_amdgcn_s_setprio(0);                                                 \
  } while (0)

#define GB_SYNC(N)                                           \
  asm volatile("s_waitcnt vmcnt(" #N ")" ::: "memory");      \
  __builtin_amdgcn_s_barrier();                              \
  asm volatile("" ::: "memory")

  // prologue: tiles 0,1 in flight (8 vmem instrs per thread)
  GB_STAGE(0, 0);
  GB_STAGE(32, 1);

  // main loop: 30 K-tiles in groups of 3 (static buffer index), peel last 2
  int kt = 64;
  #pragma unroll 1
  for (int g = 0; g < 10; ++g) {
    GB_SYNC(4);                 // tile 3g ready; next tile's 4 loads stay in flight
    GB_STAGE(kt, 2);            // prefetch tile 3g+2
    GB_COMPUTE(0);
    GB_SYNC(4);
    GB_STAGE(kt + 32, 0);
    GB_COMPUTE(1);
    GB_SYNC(4);
    GB_STAGE(kt + 64, 1);
    GB_COMPUTE(2);
    kt += 96;
  }
  GB_SYNC(4);                   // tile 30 ready (tile 31's loads remain)
  GB_COMPUTE(0);
  GB_SYNC(0);                   // tile 31: last — drain
  GB_COMPUTE(1);

#undef GB_STAGE
#undef GB_COMPUTE
#undef GB_SYNC

  #pragma unroll
  for (int i = 0; i < 8; ++i) {
    long row = m0 + wm + i * 16 + l16;
    #pragma unroll
    for (int j = 0; j < 4; ++j) {
      long col = n0 + wn + j * 16 + quad * 4;
      bf16x4 o;
      #pragma unroll
      for (int r = 0; r < 4; ++r) o[r] = (bf16_t)(acc[i][j][r]);
      *(bf16x4*)(C + row * 1024 + col) = o;
    }
  }
}

// ---------------- classifier GEMM with XCD swizzle + vectorized epilogue ----------------
__global__ __launch_bounds__(256) void k_gemm_cls(
    const bf16_t* __restrict__ q16, const bf16_t* __restrict__ w1,
    const float* __restrict__ b1, const float* __restrict__ w2,
    float* __restrict__ dsum) {
  __shared__ bf16_t sa[BM * BK];
  __shared__ bf16_t sb[BN * BK];
  int lin = ((int)blockIdx.z * 16 + blockIdx.y) * 4 + blockIdx.x;
  int c = lin & 7, j0 = lin >> 3;
  int p = c + 8 * (j0 >> 2);
  long n0 = (long)(j0 & 3) * BN;
  int s = p >> 4;
  long m0 = (long)(p & 15) * BM;
  const bf16_t* A  = q16 + (long)s * Ddim;
  const bf16_t* Bt = w1 + (long)s * Hdim * Ddim;
  f32x4 acc[4][4];
  #pragma unroll
  for (int i = 0; i < 4; ++i)
    #pragma unroll
    for (int j = 0; j < 4; ++j) acc[i][j] = (f32x4){0.f, 0.f, 0.f, 0.f};
  gemm_tile<0, 0>(A, (long)Sdim * Ddim, Bt, Ddim, m0, n0, Ddim, sa, sb, acc);
  const int tid = threadIdx.x, wave = tid >> 6, lane = tid & 63;
  const int quad = lane >> 4, l16 = lane & 15;
  const int wm = (wave & 1) * 64, wn = (wave >> 1) * 64;
  const float* b1s = b1 + (long)s * Hdim;
  const float* w2s = w2 + (long)s * Hdim;
  #pragma unroll
  for (int i = 0; i < 4; ++i) {
    float vsum = 0.f;
    #pragma unroll
    for (int j = 0; j < 4; ++j) {
      long col = n0 + wn + j * 16 + quad * 4;
      f32x4 b4 = *(const f32x4*)(b1s + col);
      f32x4 w4 = *(const f32x4*)(w2s + col);
      #pragma unroll
      for (int r = 0; r < 4; ++r)
        vsum += fmaxf(acc[i][j][r] + b4[r], 0.f) * w4[r];
    }
    vsum += __shfl_xor(vsum, 16);
    vsum += __shfl_xor(vsum, 32);
    if (lane < 16) {
      long row = m0 + wm + i * 16 + l16;
      atomicAdd(&dsum[row * Sdim + s], vsum);
    }
  }
}

// ---------------- d finalize: relu + two 16-way softmaxes ----------------
__global__ void k_finalize_d(const float* __restrict__ dsum, const float* __restrict__ cb2,
                             float* __restrict__ daws, float* __restrict__ out_da,
                             float* __restrict__ out_dv) {
  int t = blockIdx.x * 256 + threadIdx.x;   // over B*S
  int b = t >> 5, s = t & 31;
  float v = fmaxf(dsum[t] + cb2[s], 0.f);
  float m = v;
  #pragma unroll
  for (int mask = 1; mask < 16; mask <<= 1) m = fmaxf(m, __shfl_xor(m, mask));
  float e = __expf(v - m);
  float sum = e;
  #pragma unroll
  for (int mask = 1; mask < 16; mask <<= 1) sum += __shfl_xor(sum, mask);
  float r = e / sum;
  daws[t] = r;
  if (s < 16) out_da[b * 16 + s] = r;
  else        out_dv[b * 16 + (s - 16)] = r;
}

// ---------------- per-batch: scores -> softmax -> pool weights -> pooled vectors --------
#define QPAD 264
__global__ __launch_bounds__(256) void k_attn_pool(
    const bf16_t* __restrict__ q16, const bf16_t* __restrict__ G16,
    const float* __restrict__ daws, const float* __restrict__ u,
    const float* __restrict__ wv, const float* __restrict__ c0p,
    bf16_t* __restrict__ pooled) {
  __shared__ bf16_t qc[32 * QPAD];
  __shared__ bf16_t gc[32 * QPAD];
  __shared__ float sc[32][33];
  __shared__ float qup[32][8], qwp[32][8];
  __shared__ float quL[32], qwL[32], caL[32], cvL[32], daL[16], dvL[16];
  const int tid = threadIdx.x, wave = tid >> 6, lane = tid & 63;
  const int quad = lane >> 4, l16 = lane & 15;
  const long b = blockIdx.x;
  const bf16_t* qb = q16 + b * (Sdim * Ddim);
  const bf16_t* gb = G16 + b * (Sdim * Ddim);
  if (tid < 32) {
    float dval = daws[b * Sdim + tid];
    if (tid < 16) daL[tid] = dval; else dvL[tid - 16] = dval;
  }
  qup[tid >> 3][tid & 7] = 0.f;
  qwp[tid >> 3][tid & 7] = 0.f;
  const int ti = wave & 1, tj = wave >> 1;
  f32x4 acc = (f32x4){0.f, 0.f, 0.f, 0.f};
  for (int kc = 0; kc < Ddim; kc += 256) {
    __syncthreads();
    #pragma unroll
    for (int r = 0; r < 4; ++r) {
      int L = r * 256 + tid;
      int row = L >> 5, koff = (L & 31) * 8;
      *(bf16x8*)(qc + row * QPAD + koff) = *(const bf16x8*)(qb + (long)row * Ddim + kc + koff);
      *(bf16x8*)(gc + row * QPAD + koff) = *(const bf16x8*)(gb + (long)row * Ddim + kc + koff);
    }
    __syncthreads();
    #pragma unroll
    for (int kk = 0; kk < 8; ++kk) {
      bf16x8 a  = *(const bf16x8*)(gc + (ti * 16 + l16) * QPAD + kk * 32 + quad * 8);
      bf16x8 bb = *(const bf16x8*)(qc + (tj * 16 + l16) * QPAD + kk * 32 + quad * 8);
      acc = __builtin_amdgcn_mfma_f32_16x16x32_bf16(a, bb, acc, 0, 0, 0);
    }
    {
      int s2 = tid & 31, sl = tid >> 5;
      float pu = 0.f, pw = 0.f;
      const bf16_t* qrow = qc + s2 * QPAD + sl * 32;
      const float* ub = u + kc + sl * 32;
      const float* wb = wv + kc + sl * 32;
      #pragma unroll
      for (int kb = 0; kb < 4; ++kb) {
        bf16x8 qv = *(const bf16x8*)(qrow + kb * 8);
        f32x4 u0 = *(const f32x4*)(ub + kb * 8);
        f32x4 u1 = *(const f32x4*)(ub + kb * 8 + 4);
        f32x4 w0 = *(const f32x4*)(wb + kb * 8);
        f32x4 w1 = *(const f32x4*)(wb + kb * 8 + 4);
        #pragma unroll
        for (int e = 0; e < 4; ++e) {
          pu += (float)qv[e] * u0[e] + (float)qv[e + 4] * u1[e];
          pw += (float)qv[e] * w0[e] + (float)qv[e + 4] * w1[e];
        }
      }
      qup[s2][sl] += pu;
      qwp[s2][sl] += pw;
    }
  }
  __syncthreads();
  if (tid < 32) {
    float a0 = 0.f, a1 = 0.f;
    for (int k = 0; k < 8; ++k) { a0 += qup[tid][k]; a1 += qwp[tid][k]; }
    quL[tid] = a0; qwL[tid] = a1;
  }
  __syncthreads();
  {
    float c00 = c0p[0];
    int col = tj * 16 + l16;
    #pragma unroll
    for (int r = 0; r < 4; ++r) {
      int row = ti * 16 + quad * 4 + r;
      sc[row][col] = (acc[r] + quL[row] + qwL[col] + c00) * 0.03125f;
    }
  }
  __syncthreads();
  if (tid < 32) {
    float mx = -1e30f;
    for (int t = 0; t < 32; ++t) mx = fmaxf(mx, sc[tid][t]);
    float sum = 0.f;
    for (int t = 0; t < 32; ++t) { float e = __expf(sc[tid][t] - mx); sc[tid][t] = e; sum += e; }
    float inv = 1.f / sum;
    for (int t = 0; t < 32; ++t) sc[tid][t] *= inv;
  }
  __syncthreads();
  if (tid < 32) {
    float a0 = 0.f, a1 = 0.f;
    for (int s2 = 0; s2 < 16; ++s2) a0 += daL[s2] * sc[s2][tid];
    for (int s2 = 0; s2 < 16; ++s2) a1 += dvL[s2] * sc[16 + s2][tid];
    caL[tid] = a0; cvL[tid] = a1;
  }
  __syncthreads();
  {
    int d0 = tid * 4;
    float ap[4] = {0.f, 0.f, 0.f, 0.f}, vp[4] = {0.f, 0.f, 0.f, 0.f};
    for (int t = 0; t < 32; ++t) {
      float ca = caL[t], cv = cvL[t];
      bf16x4 qv = *(const bf16x4*)(qb + (long)t * Ddim + d0);
      #pragma unroll
      for (int e = 0; e < 4; ++e) {
        float x = (float)qv[e];
        ap[e] += ca * x;
        vp[e] += cv * x;
      }
    }
    bf16x4 pf, pa, pv;
    #pragma unroll
    for (int e = 0; e < 4; ++e) {
      pf[e] = (bf16_t)(0.5f * (ap[e] + vp[e]));
      pa[e] = (bf16_t)ap[e];
      pv[e] = (bf16_t)vp[e];
    }
    *(bf16x4*)(pooled + b * 3072 + d0)        = pf;
    *(bf16x4*)(pooled + b * 3072 + 1024 + d0) = pa;
    *(bf16x4*)(pooled + b * 3072 + 2048 + d0) = pv;
  }
}

// ---------------- LayerNorm + ReLU over F=512 (one wave per row) ----------------
__global__ __launch_bounds__(256) void k_ln(
    const float* __restrict__ Y,
    const float* __restrict__ fb, const float* __restrict__ fg, const float* __restrict__ fbe,
    const float* __restrict__ ab, const float* __restrict__ ag, const float* __restrict__ abe,
    const float* __restrict__ vb, const float* __restrict__ vg, const float* __restrict__ vbe,
    float* __restrict__ out) {
  int wave = threadIdx.x >> 6, lane = threadIdx.x & 63;
  long row = (long)blockIdx.x * 4 + wave;        // [0, 3*B)
  int head = (int)(row >> 11);
  const float* bb = (head == 0) ? fb : (head == 1) ? ab : vb;
  const float* gg = (head == 0) ? fg : (head == 1) ? ag : vg;
  const float* be = (head == 0) ? fbe : (head == 1) ? abe : vbe;
  const float* y = Y + row * Fdim + lane * 8;
  float v[8];
  float s = 0.f;
  #pragma unroll
  for (int k = 0; k < 8; ++k) { v[k] = y[k] + bb[lane * 8 + k]; s += v[k]; }
  #pragma unroll
  for (int m = 1; m < 64; m <<= 1) s += __shfl_xor(s, m);
  float mu = s * (1.f / Fdim);
  float vs = 0.f;
  #pragma unroll
  for (int k = 0; k < 8; ++k) { float t = v[k] - mu; vs += t * t; }
  #pragma unroll
  for (int m = 1; m < 64; m <<= 1) vs += __shfl_xor(vs, m);
  float inv = rsqrtf(vs * (1.f / Fdim) + 1e-5f);
  float* o = out + row * Fdim + lane * 8;
  #pragma unroll
  for (int k = 0; k < 8; ++k) {
    float t = (v[k] - mu) * inv * gg[lane * 8 + k] + be[lane * 8 + k];
    o[k] = fmaxf(t, 0.f);
  }
}

// ---------------- launch ----------------
extern "C" void kernel_launch(void* const* d_in, const int* in_sizes, int n_in,
                              void* d_out, int out_size, void* d_ws, size_t ws_size,
                              hipStream_t stream) {
  const float* q    = (const float*)d_in[0];
  const float* ipw  = (const float*)d_in[1];
  const float* ipb  = (const float*)d_in[2];
  const float* ow   = (const float*)d_in[3];
  const float* ob   = (const float*)d_in[4];
  const float* cw1  = (const float*)d_in[5];
  const float* cb1  = (const float*)d_in[6];
  const float* cw2  = (const float*)d_in[7];
  const float* cb2  = (const float*)d_in[8];
  const float* fusw = (const float*)d_in[9];
  const float* fusb = (const float*)d_in[10];
  const float* fusg = (const float*)d_in[11];
  const float* fusbe= (const float*)d_in[12];
  const float* paw  = (const float*)d_in[13];
  const float* pab  = (const float*)d_in[14];
  const float* pag  = (const float*)d_in[15];
  const float* pabe = (const float*)d_in[16];
  const float* pvw  = (const float*)d_in[17];
  const float* pvb  = (const float*)d_in[18];
  const float* pvg  = (const float*)d_in[19];
  const float* pvbe = (const float*)d_in[20];
  float* out = (float*)d_out;

  // workspace layout (bytes)
  const size_t o_q16   = 0;                    // 134217728
  const size_t o_w16   = 134217728;            // 6291456 (Wq,Wk,Wv)
  const size_t o_ow16  = 140509184;            // 2097152
  const size_t o_cls16 = 142606336;            // 33554432
  const size_t o_hw16  = 176160768;            // 3145728 (fus,pa,pv)
  const size_t o_Mt    = 179306496;            // 2097152
  const size_t o_Nt    = 181403648;            // 2097152
  const size_t o_G16   = 183500800;            // 134217728 (aliased later by S1,Y)
  const size_t o_pool  = 317718528;            // 12582912
  const size_t o_u     = 330301440;            // 4096
  const size_t o_wv    = 330305536;            // 4096
  const size_t o_bp    = 330309632;            // 4096
  const size_t o_c0    = 330313728;            // 256
  const size_t o_dsum  = 330313984;            // 262144
  const size_t o_daws  = 330576128;            // 262144
  const size_t total   = 330838272;
  if (ws_size < total) return;

  char* ws = (char*)d_ws;
  bf16_t* q16   = (bf16_t*)(ws + o_q16);
  bf16_t* w16   = (bf16_t*)(ws + o_w16);
  bf16_t* Wq16  = w16;
  bf16_t* Wk16  = w16 + 1048576;
  bf16_t* Wv16  = w16 + 2097152;
  bf16_t* ow16  = (bf16_t*)(ws + o_ow16);
  bf16_t* cls16 = (bf16_t*)(ws + o_cls16);
  bf16_t* hw16  = (bf16_t*)(ws + o_hw16);
  bf16_t* Mt    = (bf16_t*)(ws + o_Mt);
  bf16_t* Nt    = (bf16_t*)(ws + o_Nt);
  bf16_t* G16   = (bf16_t*)(ws + o_G16);
  bf16_t* S116  = (bf16_t*)(ws + o_G16);                 // alias (G16 dead by then)
  float*  Yf    = (float*)(ws + o_G16 + 12582912);       // alias
  bf16_t* pool16= (bf16_t*)(ws + o_pool);
  float*  uf    = (float*)(ws + o_u);
  float*  wvf   = (float*)(ws + o_wv);
  float*  bpf   = (float*)(ws + o_bp);
  float*  c0f   = (float*)(ws + o_c0);
  float*  dsum  = (float*)(ws + o_dsum);
  float*  daws  = (float*)(ws + o_daws);

  // 1) one fused convert for everything
  k_cvt_all<<<dim3(87552), dim3(256), 0, stream>>>(
      q, ipw, ow, cw1, fusw, paw, pvw, q16, w16, ow16, cls16, hw16);

  // 2) bias precompute
  k_bias_pre<<<dim3(137), dim3(256), 0, stream>>>(ipw, ipb, ow, ob, uf, wvf, bpf, c0f);

  // 3) M^T = Wk^T Wq
  k_gemm_bf16<1, 1><<<dim3(8, 8, 1), dim3(256), 0, stream>>>(
      Wk16, Ddim, 0, Wq16, Ddim, 0, Mt, Ddim, 0, nullptr, Ddim);

  // 4) N^T = Wo @ Wv
  k_gemm_bf16<0, 1><<<dim3(8, 8, 1), dim3(256), 0, stream>>>(
      ow16, Ddim, 0, Wv16, Ddim, 0, Nt, Ddim, 0, nullptr, Ddim);

  // 5) G = q16 @ M   (256x256 tile, BK=32, triple-buffer counted-vmcnt pipeline)
  k_gemm_big<<<dim3(1024), dim3(512), 0, stream>>>(q16, Mt, G16);

  // 6) classifier
  hipMemsetAsync(dsum, 0, (size_t)Bdim * Sdim * sizeof(float), stream);
  k_gemm_cls<<<dim3(4, 16, 32), dim3(256), 0, stream>>>(q16, cls16, cb1, cw2, dsum);

  // 7) d -> softmaxes -> d_a,d_v
  k_finalize_d<<<dim3(256), dim3(256), 0, stream>>>(
      dsum, cb2, daws, out + 3145728, out + 3145728 + 32768);

  // 8) per-batch attention scores + pooling
  k_attn_pool<<<dim3(2048), dim3(256), 0, stream>>>(q16, G16, daws, uf, wvf, c0f, pool16);

  // 9) S1 = pooled @ N + b'
  k_gemm_bf16<0, 0><<<dim3(8, 48, 1), dim3(256), 0, stream>>>(
      pool16, Ddim, 0, Nt, Ddim, 0, S116, Ddim, 0, bpf, Ddim);

  // 10) heads: Y[z] = S1[:,z,:] @ headw[z]^T
  k_gemm_f32<<<dim3(4, 16, 3), dim3(256), 0, stream>>>(
      S116, 3L * Ddim, Ddim, hw16, Ddim, (long)Fdim * Ddim,
      Yf, Fdim, (long)Bdim * Fdim, Ddim);

  // 11) LN + ReLU -> out
  k_ln<<<dim3(1536), dim3(256), 0, stream>>>(
      Yf, fusb, fusg, fusbe, pab, pag, pabe, pvb, pvg, pvbe, out);
}

// Round 2
// 1032.512 us; speedup vs baseline: 1.0105x; 1.0105x over previous
//
#include <hip/hip_runtime.h>

// Problem constants
#define Bdim 2048
#define Sdim 32
#define Ddim 1024
#define Fdim 512
#define Hdim 512

typedef __bf16 bf16_t;
typedef __bf16 bf16x8 __attribute__((ext_vector_type(8)));
typedef __bf16 bf16x4 __attribute__((ext_vector_type(4)));
typedef float  f32x4  __attribute__((ext_vector_type(4)));

#define BM 128
#define BN 128
#define BK 32

// ---------------- async global->LDS, 16B per lane ----------------
__device__ __forceinline__ void gll16(const bf16_t* g, bf16_t* l) {
  __builtin_amdgcn_global_load_lds((const __attribute__((address_space(1))) void*)g,
                                   (__attribute__((address_space(3))) void*)l,
                                   16, 0, 0);
}

// XOR-swizzled LDS offset for BK=32 tiles: slot (row, k-chunk c) holds global chunk
// c ^ ((row>>1)&3). Staging stays lane-contiguous (global_load_lds compatible) and
// fully coalesced; fragment reads spread across all 8 bank groups (2-way = free).
__device__ __forceinline__ int swz32(int row, int k) {
  return row * 32 + (((((k >> 3) ^ ((row >> 1) & 3))) << 3) | (k & 7));
}

// ---------------- fused fp32 -> bf16 convert for ALL weight/input tensors ----------------
__global__ void k_cvt_all(const float* __restrict__ q, const float* __restrict__ ipw,
                          const float* __restrict__ ow, const float* __restrict__ cw1,
                          const float* __restrict__ fusw, const float* __restrict__ paw,
                          const float* __restrict__ pvw,
                          bf16_t* __restrict__ q16, bf16_t* __restrict__ w16,
                          bf16_t* __restrict__ ow16, bf16_t* __restrict__ cls16,
                          bf16_t* __restrict__ hw16) {
  long v = (long)blockIdx.x * 256 + threadIdx.x;
  const float* s; bf16_t* d; long off;
  if (v < 16777216L)      { s = q;    d = q16;            off = 0; }
  else if (v < 17563648L) { s = ipw;  d = w16;            off = 16777216L; }
  else if (v < 17825792L) { s = ow;   d = ow16;           off = 17563648L; }
  else if (v < 22020096L) { s = cw1;  d = cls16;          off = 17825792L; }
  else if (v < 22151168L) { s = fusw; d = hw16;           off = 22020096L; }
  else if (v < 22282240L) { s = paw;  d = hw16 + 524288;  off = 22151168L; }
  else                    { s = pvw;  d = hw16 + 1048576; off = 22282240L; }
  long i = (v - off) * 4;
  float4 t = *(const float4*)(s + i);
  bf16x4 o;
  o[0] = (bf16_t)t.x; o[1] = (bf16_t)t.y; o[2] = (bf16_t)t.z; o[3] = (bf16_t)t.w;
  *(bf16x4*)(d + i) = o;
}

// ---------------- bias precompute: u = Wq^T bk, w = Wk^T bq, b' = Wo bv + out_b, c0 = bq.bk
__global__ void k_bias_pre(const float* __restrict__ ipw, const float* __restrict__ ipb,
                           const float* __restrict__ ow, const float* __restrict__ ob,
                           float* __restrict__ u, float* __restrict__ w,
                           float* __restrict__ bp, float* __restrict__ c0) {
  int blk = blockIdx.x, tid = threadIdx.x;
  if (blk < 4) {
    int d = blk * 256 + tid;
    float acc = 0.f;
    #pragma unroll 8
    for (int e = 0; e < Ddim; ++e) acc += ipw[(long)e * Ddim + d] * ipb[Ddim + e];
    u[d] = acc;
  } else if (blk < 8) {
    int d = (blk - 4) * 256 + tid;
    float acc = 0.f;
    #pragma unroll 8
    for (int e = 0; e < Ddim; ++e) acc += ipw[(long)(Ddim + e) * Ddim + d] * ipb[e];
    w[d] = acc;
  } else if (blk < 136) {
    int o = (blk - 8) * 8 + (tid >> 5);
    int l = tid & 31;
    float acc = 0.f;
    #pragma unroll 4
    for (int e = l; e < Ddim; e += 32) acc += ow[(long)o * Ddim + e] * ipb[2 * Ddim + e];
    #pragma unroll
    for (int m = 1; m < 32; m <<= 1) acc += __shfl_xor(acc, m);
    if (l == 0) bp[o] = acc + ob[o];
  } else {
    __shared__ float red[256];
    float acc = 0.f;
    for (int e = tid; e < Ddim; e += 256) acc += ipb[e] * ipb[Ddim + e];
    red[tid] = acc;
    __syncthreads();
    for (int off = 128; off; off >>= 1) {
      if (tid < off) red[tid] += red[tid + off];
      __syncthreads();
    }
    if (tid == 0) c0[0] = red[0];
  }
}

// ---------------- generic 128x128x32 MFMA mainloop (operand-swapped mfma, swizzled LDS) --
// acc[i][j][r] = C[m0+wm+i*16+l16][n0+wn+j*16+quad*4+r]
template<int AT, int BT>
__device__ __forceinline__ void gemm_tile(const bf16_t* __restrict__ A, long lda,
                                          const bf16_t* __restrict__ Bt, long ldb,
                                          long m0, long n0, int K,
                                          bf16_t* sa, bf16_t* sb, f32x4 acc[4][4]) {
  const int tid  = threadIdx.x;
  const int wave = tid >> 6;
  const int lane = tid & 63;
  const int quad = lane >> 4;
  const int l16  = lane & 15;
  const int wm = (wave & 1) * 64;
  const int wn = (wave >> 1) * 64;

  for (int kt = 0; kt < K; kt += BK) {
    __syncthreads();
    if constexpr (AT == 0) {
      #pragma unroll
      for (int r = 0; r < 2; ++r) {
        int L = r * 256 + tid;
        int row = L >> 2, cs = L & 3;
        int csrc = cs ^ ((row >> 1) & 3);
        gll16(A + (m0 + row) * lda + kt + csrc * 8, sa + (long)(r * 256 + wave * 64) * 8);
      }
    } else {
      #pragma unroll
      for (int r = 0; r < 2; ++r) {
        int L = r * 256 + tid;
        int gk = L >> 4, gm = (L & 15) * 8;
        bf16x8 v = *(const bf16x8*)(A + (long)(kt + gk) * lda + m0 + gm);
        #pragma unroll
        for (int j = 0; j < 8; ++j) sa[swz32(gm + j, gk)] = v[j];
      }
    }
    if constexpr (BT == 0) {
      #pragma unroll
      for (int r = 0; r < 2; ++r) {
        int L = r * 256 + tid;
        int row = L >> 2, cs = L & 3;
        int csrc = cs ^ ((row >> 1) & 3);
        gll16(Bt + (n0 + row) * ldb + kt + csrc * 8, sb + (long)(r * 256 + wave * 64) * 8);
      }
    } else {
      #pragma unroll
      for (int r = 0; r < 2; ++r) {
        int L = r * 256 + tid;
        int gk = L >> 4, gn = (L & 15) * 8;
        bf16x8 v = *(const bf16x8*)(Bt + (long)(kt + gk) * ldb + n0 + gn);
        #pragma unroll
        for (int j = 0; j < 8; ++j) sb[swz32(gn + j, gk)] = v[j];
      }
    }
    __syncthreads();
    bf16x8 af[4], bfr[4];
    #pragma unroll
    for (int i = 0; i < 4; ++i) {
      int row = wm + i * 16 + l16;
      af[i] = *(const bf16x8*)(sa + row * 32 + ((quad ^ ((row >> 1) & 3)) << 3));
    }
    #pragma unroll
    for (int j = 0; j < 4; ++j) {
      int row = wn + j * 16 + l16;
      bfr[j] = *(const bf16x8*)(sb + row * 32 + ((quad ^ ((row >> 1) & 3)) << 3));
    }
    #pragma unroll
    for (int i = 0; i < 4; ++i)
      #pragma unroll
      for (int j = 0; j < 4; ++j)
        acc[i][j] = __builtin_amdgcn_mfma_f32_16x16x32_bf16(bfr[j], af[i], acc[i][j], 0, 0, 0);
  }
}

// ---------------- GEMM with bf16 output (+optional fp32 bias on n), vectorized stores ----
template<int AT, int BT>
__global__ __launch_bounds__(256) void k_gemm_bf16(
    const bf16_t* __restrict__ A, long lda, long sAz,
    const bf16_t* __restrict__ Bt, long ldb, long sBz,
    bf16_t* __restrict__ C, long ldc, long sCz,
    const float* __restrict__ bias, int K) {
  __shared__ bf16_t sa[BM * BK];
  __shared__ bf16_t sb[BN * BK];
  long n0 = (long)blockIdx.x * BN;
  long m0 = (long)blockIdx.y * BM;
  long z  = blockIdx.z;
  const bf16_t* Az = A + z * sAz;
  const bf16_t* Bz = Bt + z * sBz;
  bf16_t* Cz = C + z * sCz;
  f32x4 acc[4][4];
  #pragma unroll
  for (int i = 0; i < 4; ++i)
    #pragma unroll
    for (int j = 0; j < 4; ++j) acc[i][j] = (f32x4){0.f, 0.f, 0.f, 0.f};
  gemm_tile<AT, BT>(Az, lda, Bz, ldb, m0, n0, K, sa, sb, acc);
  const int tid = threadIdx.x, wave = tid >> 6, lane = tid & 63;
  const int quad = lane >> 4, l16 = lane & 15;
  const int wm = (wave & 1) * 64, wn = (wave >> 1) * 64;
  #pragma unroll
  for (int i = 0; i < 4; ++i) {
    long row = m0 + wm + i * 16 + l16;
    #pragma unroll
    for (int j = 0; j < 4; ++j) {
      long col = n0 + wn + j * 16 + quad * 4;
      f32x4 b4 = bias ? *(const f32x4*)(bias + col) : (f32x4){0.f, 0.f, 0.f, 0.f};
      bf16x4 o;
      #pragma unroll
      for (int r = 0; r < 4; ++r) o[r] = (bf16_t)(acc[i][j][r] + b4[r]);
      *(bf16x4*)(Cz + row * ldc + col) = o;
    }
  }
}

// ---------------- GEMM with fp32 output (heads), vectorized f32x4 stores ----------------
__global__ __launch_bounds__(256) void k_gemm_f32(
    const bf16_t* __restrict__ A, long lda, long sAz,
    const bf16_t* __restrict__ Bt, long ldb, long sBz,
    float* __restrict__ C, long ldc, long sCz, int K) {
  __shared__ bf16_t sa[BM * BK];
  __shared__ bf16_t sb[BN * BK];
  long n0 = (long)blockIdx.x * BN;
  long m0 = (long)blockIdx.y * BM;
  long z  = blockIdx.z;
  const bf16_t* Az = A + z * sAz;
  const bf16_t* Bz = Bt + z * sBz;
  float* Cz = C + z * sCz;
  f32x4 acc[4][4];
  #pragma unroll
  for (int i = 0; i < 4; ++i)
    #pragma unroll
    for (int j = 0; j < 4; ++j) acc[i][j] = (f32x4){0.f, 0.f, 0.f, 0.f};
  gemm_tile<0, 0>(Az, lda, Bz, ldb, m0, n0, K, sa, sb, acc);
  const int tid = threadIdx.x, wave = tid >> 6, lane = tid & 63;
  const int quad = lane >> 4, l16 = lane & 15;
  const int wm = (wave & 1) * 64, wn = (wave >> 1) * 64;
  #pragma unroll
  for (int i = 0; i < 4; ++i) {
    long row = m0 + wm + i * 16 + l16;
    #pragma unroll
    for (int j = 0; j < 4; ++j) {
      long col = n0 + wn + j * 16 + quad * 4;
      *(f32x4*)(Cz + row * ldc + col) = acc[i][j];
    }
  }
}

// ---------------- big-tile GEMM for G = q16 @ M : 256x256, BK=64, 8-phase schedule -------
// T2(XOR swizzle) + T3/T4(per-quadrant phases, counted vmcnt(4), never 0 in loop) +
// T5(setprio). Double-buffered LDS 128KB (1 block/CU). Per K-tile: 4 phases, each =
// { ds_read frag subtile | issue 2 stage-ops (8KB each) for tile X+1 | barrier |
//   lgkmcnt(0)+sched_barrier | setprio(1) 16 MFMA setprio(0) | [vmcnt(4)] barrier }.
// Quadrant order (n0,m0)(n1,m0)(n1,m1)(n0,m1): af persists 2 phases, bfr0 persists to P4
// -> minimal 24 ds_read_b128/wave/tile. Region lifetimes: every stage target's last
// ds_read is >=2 phases earlier and drained by that phase's lgkmcnt(0) before its
// trailing barrier. FIFO issue order == deadline order -> every gate is vmcnt(4):
//   end P4: needs Aq0,Aq2,BoEven(X+1) (4 oldest) -> 4 newer outstanding
//   end P1: needs BoOdd(X)              -> 4 newer;  end P2: needs Aq1,Aq3(X) -> 4 newer
//   end P3: no gate (P4 reads only persisted regs).
// Tail tiles stage k>=1024: reads land in adjacent mapped ws regions (w16/Nt), data never
// consumed (tiles 16/17 never computed) -- no epilogue branches needed.
__global__ __launch_bounds__(512, 2) void k_gemm_big8(
    const bf16_t* __restrict__ A, const bf16_t* __restrict__ Bt,
    bf16_t* __restrict__ C) {
  __shared__ bf16_t sa[2][256 * 64];   // 2 x 32 KB
  __shared__ bf16_t sb[2][256 * 64];   // 2 x 32 KB
  const int tid = threadIdx.x, wave = tid >> 6, lane = tid & 63;
  const int quad = lane >> 4, l16 = lane & 15;
  // grid 1024; bijective XCD swizzle, n-inner for A-panel L2 reuse
  int lin = blockIdx.x;
  int c = lin & 7, t0 = lin >> 3;
  int wg = c * 128 + t0;
  long m0 = (long)(wg >> 2) * 256;
  long n0 = (long)(wg & 3) * 256;
  const int wm = (wave >> 2) * 128;     // 2 waves in M
  const int wn = (wave & 3) * 64;       // 4 waves in N

  // ---- staging addressing (pre-swizzled global source, linear LDS dest) ----
  // A quarter Q (rows Q*64..Q*64+63): thread t covers row Q*64+(t>>3), chunk t&7.
  const int csA = tid & 7;
  const bf16_t* aSrc = A + (m0 + (tid >> 3)) * 1024 + (long)((csA ^ ((tid >> 4) & 7)) * 8);
  // B octant (rows oct*32..+31) by 4-wave group: t2 = tid&255 covers 32 rows x 8 chunks.
  const int t2 = tid & 255;
  const bf16_t* bSrc = Bt + (n0 + (t2 >> 3)) * 1024 + (long)(((t2 & 7) ^ ((t2 >> 4) & 7)) * 8);

  // ---- fragment read addressing ----
  // elem(row, chunk cc) = row*64 + ((cc ^ ((row>>1)&7))<<3); (row>>1)&7 == l16>>1 here.
  const int swzk0 = ((0 * 4 + quad) ^ (l16 >> 1)) << 3;
  const int swzk1 = ((1 * 4 + quad) ^ (l16 >> 1)) << 3;
  const int aBase = (wm + l16) * 64;
  const int bBase = (wn + l16) * 64;

  f32x4 acc[8][4];
  #pragma unroll
  for (int i = 0; i < 8; ++i)
    #pragma unroll
    for (int j = 0; j < 4; ++j) acc[i][j] = (f32x4){0.f, 0.f, 0.f, 0.f};

  bf16x8 afc[8], bfr0[4], bfr1[4];

#define ST_AQ(SB, KT, Q) \
  gll16(aSrc + (long)(Q) * 65536 + (KT), &sa[SB][(Q) * 4096 + wave * 512])
#define ST_BP(SB, KT, OA, OB) do {                                             \
    int oct_ = (wave < 4) ? (OA) : (OB);                                       \
    gll16(bSrc + (long)oct_ * 32768 + (KT),                                    \
          &sb[SB][oct_ * 2048 + (wave & 3) * 512]);                            \
  } while (0)

#define LD_AF(CB, MH) do {                                                     \
    _Pragma("unroll")                                                          \
    for (int i = 0; i < 4; ++i) {                                              \
      afc[i * 2 + 0] = *(const bf16x8*)(&sa[CB][aBase + (MH) * 4096 + i * 1024 + swzk0]); \
      afc[i * 2 + 1] = *(const bf16x8*)(&sa[CB][aBase + (MH) * 4096 + i * 1024 + swzk1]); \
    } } while (0)
#define LD_BF(CB, NH, DST) do {                                                \
    _Pragma("unroll")                                                          \
    for (int jj = 0; jj < 2; ++jj) {                                           \
      DST[jj * 2 + 0] = *(const bf16x8*)(&sb[CB][bBase + (NH) * 2048 + jj * 1024 + swzk0]); \
      DST[jj * 2 + 1] = *(const bf16x8*)(&sb[CB][bBase + (NH) * 2048 + jj * 1024 + swzk1]); \
    } } while (0)

#define MFMA16(BF, IOFF, JOFF) do {                                            \
    __builtin_amdgcn_s_setprio(1);                                             \
    _Pragma("unroll")                                                          \
    for (int i = 0; i < 4; ++i)                                                \
      _Pragma("unroll")                                                        \
      for (int jj = 0; jj < 2; ++jj)                                           \
        _Pragma("unroll")                                                      \
        for (int kh = 0; kh < 2; ++kh)                                         \
          acc[(IOFF) + i][(JOFF) + jj] = __builtin_amdgcn_mfma_f32_16x16x32_bf16( \
              BF[jj * 2 + kh], afc[i * 2 + kh], acc[(IOFF) + i][(JOFF) + jj], 0, 0, 0); \
    __builtin_amdgcn_s_setprio(0);                                             \
    __builtin_amdgcn_sched_barrier(0);                                         \
  } while (0)

#define BAR1() do {                                                            \
    asm volatile("" ::: "memory");                                             \
    __builtin_amdgcn_s_barrier();                                              \
    asm volatile("s_waitcnt lgkmcnt(0)" ::: "memory");                         \
    __builtin_amdgcn_sched_barrier(0);                                         \
  } while (0)
#define BAR2V() do {                                                           \
    asm volatile("s_waitcnt vmcnt(4)" ::: "memory");                           \
    __builtin_amdgcn_s_barrier();                                              \
    asm volatile("" ::: "memory");                                             \
  } while (0)
#define BAR2() do {                                                            \
    asm volatile("" ::: "memory");                                             \
    __builtin_amdgcn_s_barrier();                                              \
    asm volatile("" ::: "memory");                                             \
  } while (0)

  // tile X computed from buffer CB; stages for tile X+1 go into SB=CB^1 at k-offset KT2
#define TILE(CB, SB, KT2) do {                                                 \
    /* P1: quadrant (n0, m0) */                                                \
    LD_AF(CB, 0); LD_BF(CB, 0, bfr0);                                          \
    ST_AQ(SB, KT2, 0); ST_AQ(SB, KT2, 2);                                      \
    BAR1(); MFMA16(bfr0, 0, 0); BAR2V();                                       \
    /* P2: quadrant (n1, m0) */                                                \
    LD_BF(CB, 1, bfr1);                                                        \
    ST_BP(SB, KT2, 0, 4); ST_BP(SB, KT2, 2, 6);                                \
    BAR1(); MFMA16(bfr1, 0, 2); BAR2V();                                       \
    /* P3: quadrant (n1, m1) */                                                \
    LD_AF(CB, 1);                                                              \
    ST_BP(SB, KT2, 1, 5); ST_BP(SB, KT2, 3, 7);                                \
    BAR1(); MFMA16(bfr1, 4, 2); BAR2();                                        \
    /* P4: quadrant (n0, m1) -- no ds_read, all operands persisted */          \
    ST_AQ(SB, KT2, 1); ST_AQ(SB, KT2, 3);                                      \
    BAR1(); MFMA16(bfr0, 4, 0); BAR2V();                                       \
  } while (0)

  // prologue: tile 0 into buf0, FIFO order == deadline order
  ST_AQ(0, 0, 0); ST_AQ(0, 0, 2);
  ST_BP(0, 0, 0, 4); ST_BP(0, 0, 2, 6);
  ST_BP(0, 0, 1, 5); ST_BP(0, 0, 3, 7);
  ST_AQ(0, 0, 1); ST_AQ(0, 0, 3);
  BAR2V();

  #pragma unroll 1
  for (int x = 0; x < 16; x += 2) {
    int ktA = (x + 1) * 64;
    int ktB = (x + 2) * 64;   // x=14 -> 1024: harmless in-workspace garbage reads
    TILE(0, 1, ktA);
    TILE(1, 0, ktB);
  }

#undef ST_AQ
#undef ST_BP
#undef LD_AF
#undef LD_BF
#undef MFMA16
#undef BAR1
#undef BAR2V
#undef BAR2
#undef TILE

  #pragma unroll
  for (int i = 0; i < 8; ++i) {
    long row = m0 + wm + i * 16 + l16;
    #pragma unroll
    for (int j = 0; j < 4; ++j) {
      long col = n0 + wn + j * 16 + quad * 4;
      bf16x4 o;
      #pragma unroll
      for (int r = 0; r < 4; ++r) o[r] = (bf16_t)(acc[i][j][r]);
      *(bf16x4*)(C + row * 1024 + col) = o;
    }
  }
}

// ---------------- classifier GEMM with XCD swizzle + vectorized epilogue ----------------
__global__ __launch_bounds__(256) void k_gemm_cls(
    const bf16_t* __restrict__ q16, const bf16_t* __restrict__ w1,
    const float* __restrict__ b1, const float* __restrict__ w2,
    float* __restrict__ dsum) {
  __shared__ bf16_t sa[BM * BK];
  __shared__ bf16_t sb[BN * BK];
  int lin = ((int)blockIdx.z * 16 + blockIdx.y) * 4 + blockIdx.x;
  int c = lin & 7, j0 = lin >> 3;
  int p = c + 8 * (j0 >> 2);
  long n0 = (long)(j0 & 3) * BN;
  int s = p >> 4;
  long m0 = (long)(p & 15) * BM;
  const bf16_t* A  = q16 + (long)s * Ddim;
  const bf16_t* Bt = w1 + (long)s * Hdim * Ddim;
  f32x4 acc[4][4];
  #pragma unroll
  for (int i = 0; i < 4; ++i)
    #pragma unroll
    for (int j = 0; j < 4; ++j) acc[i][j] = (f32x4){0.f, 0.f, 0.f, 0.f};
  gemm_tile<0, 0>(A, (long)Sdim * Ddim, Bt, Ddim, m0, n0, Ddim, sa, sb, acc);
  const int tid = threadIdx.x, wave = tid >> 6, lane = tid & 63;
  const int quad = lane >> 4, l16 = lane & 15;
  const int wm = (wave & 1) * 64, wn = (wave >> 1) * 64;
  const float* b1s = b1 + (long)s * Hdim;
  const float* w2s = w2 + (long)s * Hdim;
  #pragma unroll
  for (int i = 0; i < 4; ++i) {
    float vsum = 0.f;
    #pragma unroll
    for (int j = 0; j < 4; ++j) {
      long col = n0 + wn + j * 16 + quad * 4;
      f32x4 b4 = *(const f32x4*)(b1s + col);
      f32x4 w4 = *(const f32x4*)(w2s + col);
      #pragma unroll
      for (int r = 0; r < 4; ++r)
        vsum += fmaxf(acc[i][j][r] + b4[r], 0.f) * w4[r];
    }
    vsum += __shfl_xor(vsum, 16);
    vsum += __shfl_xor(vsum, 32);
    if (lane < 16) {
      long row = m0 + wm + i * 16 + l16;
      atomicAdd(&dsum[row * Sdim + s], vsum);
    }
  }
}

// ---------------- d finalize: relu + two 16-way softmaxes ----------------
__global__ void k_finalize_d(const float* __restrict__ dsum, const float* __restrict__ cb2,
                             float* __restrict__ daws, float* __restrict__ out_da,
                             float* __restrict__ out_dv) {
  int t = blockIdx.x * 256 + threadIdx.x;   // over B*S
  int b = t >> 5, s = t & 31;
  float v = fmaxf(dsum[t] + cb2[s], 0.f);
  float m = v;
  #pragma unroll
  for (int mask = 1; mask < 16; mask <<= 1) m = fmaxf(m, __shfl_xor(m, mask));
  float e = __expf(v - m);
  float sum = e;
  #pragma unroll
  for (int mask = 1; mask < 16; mask <<= 1) sum += __shfl_xor(sum, mask);
  float r = e / sum;
  daws[t] = r;
  if (s < 16) out_da[b * 16 + s] = r;
  else        out_dv[b * 16 + (s - 16)] = r;
}

// ---------------- per-batch: scores -> softmax -> pool weights -> pooled vectors --------
#define QPAD 264
__global__ __launch_bounds__(256) void k_attn_pool(
    const bf16_t* __restrict__ q16, const bf16_t* __restrict__ G16,
    const float* __restrict__ daws, const float* __restrict__ u,
    const float* __restrict__ wv, const float* __restrict__ c0p,
    bf16_t* __restrict__ pooled) {
  __shared__ bf16_t qc[32 * QPAD];
  __shared__ bf16_t gc[32 * QPAD];
  __shared__ float sc[32][33];
  __shared__ float qup[32][8], qwp[32][8];
  __shared__ float quL[32], qwL[32], caL[32], cvL[32], daL[16], dvL[16];
  const int tid = threadIdx.x, wave = tid >> 6, lane = tid & 63;
  const int quad = lane >> 4, l16 = lane & 15;
  const long b = blockIdx.x;
  const bf16_t* qb = q16 + b * (Sdim * Ddim);
  const bf16_t* gb = G16 + b * (Sdim * Ddim);
  if (tid < 32) {
    float dval = daws[b * Sdim + tid];
    if (tid < 16) daL[tid] = dval; else dvL[tid - 16] = dval;
  }
  qup[tid >> 3][tid & 7] = 0.f;
  qwp[tid >> 3][tid & 7] = 0.f;
  const int ti = wave & 1, tj = wave >> 1;
  f32x4 acc = (f32x4){0.f, 0.f, 0.f, 0.f};
  for (int kc = 0; kc < Ddim; kc += 256) {
    __syncthreads();
    #pragma unroll
    for (int r = 0; r < 4; ++r) {
      int L = r * 256 + tid;
      int row = L >> 5, koff = (L & 31) * 8;
      *(bf16x8*)(qc + row * QPAD + koff) = *(const bf16x8*)(qb + (long)row * Ddim + kc + koff);
      *(bf16x8*)(gc + row * QPAD + koff) = *(const bf16x8*)(gb + (long)row * Ddim + kc + koff);
    }
    __syncthreads();
    #pragma unroll
    for (int kk = 0; kk < 8; ++kk) {
      bf16x8 a  = *(const bf16x8*)(gc + (ti * 16 + l16) * QPAD + kk * 32 + quad * 8);
      bf16x8 bb = *(const bf16x8*)(qc + (tj * 16 + l16) * QPAD + kk * 32 + quad * 8);
      acc = __builtin_amdgcn_mfma_f32_16x16x32_bf16(a, bb, acc, 0, 0, 0);
    }
    {
      int s2 = tid & 31, sl = tid >> 5;
      float pu = 0.f, pw = 0.f;
      const bf16_t* qrow = qc + s2 * QPAD + sl * 32;
      const float* ub = u + kc + sl * 32;
      const float* wb = wv + kc + sl * 32;
      #pragma unroll
      for (int kb = 0; kb < 4; ++kb) {
        bf16x8 qv = *(const bf16x8*)(qrow + kb * 8);
        f32x4 u0 = *(const f32x4*)(ub + kb * 8);
        f32x4 u1 = *(const f32x4*)(ub + kb * 8 + 4);
        f32x4 w0 = *(const f32x4*)(wb + kb * 8);
        f32x4 w1 = *(const f32x4*)(wb + kb * 8 + 4);
        #pragma unroll
        for (int e = 0; e < 4; ++e) {
          pu += (float)qv[e] * u0[e] + (float)qv[e + 4] * u1[e];
          pw += (float)qv[e] * w0[e] + (float)qv[e + 4] * w1[e];
        }
      }
      qup[s2][sl] += pu;
      qwp[s2][sl] += pw;
    }
  }
  __syncthreads();
  if (tid < 32) {
    float a0 = 0.f, a1 = 0.f;
    for (int k = 0; k < 8; ++k) { a0 += qup[tid][k]; a1 += qwp[tid][k]; }
    quL[tid] = a0; qwL[tid] = a1;
  }
  __syncthreads();
  {
    float c00 = c0p[0];
    int col = tj * 16 + l16;
    #pragma unroll
    for (int r = 0; r < 4; ++r) {
      int row = ti * 16 + quad * 4 + r;
      sc[row][col] = (acc[r] + quL[row] + qwL[col] + c00) * 0.03125f;
    }
  }
  __syncthreads();
  if (tid < 32) {
    float mx = -1e30f;
    for (int t = 0; t < 32; ++t) mx = fmaxf(mx, sc[tid][t]);
    float sum = 0.f;
    for (int t = 0; t < 32; ++t) { float e = __expf(sc[tid][t] - mx); sc[tid][t] = e; sum += e; }
    float inv = 1.f / sum;
    for (int t = 0; t < 32; ++t) sc[tid][t] *= inv;
  }
  __syncthreads();
  if (tid < 32) {
    float a0 = 0.f, a1 = 0.f;
    for (int s2 = 0; s2 < 16; ++s2) a0 += daL[s2] * sc[s2][tid];
    for (int s2 = 0; s2 < 16; ++s2) a1 += dvL[s2] * sc[16 + s2][tid];
    caL[tid] = a0; cvL[tid] = a1;
  }
  __syncthreads();
  {
    int d0 = tid * 4;
    float ap[4] = {0.f, 0.f, 0.f, 0.f}, vp[4] = {0.f, 0.f, 0.f, 0.f};
    for (int t = 0; t < 32; ++t) {
      float ca = caL[t], cv = cvL[t];
      bf16x4 qv = *(const bf16x4*)(qb + (long)t * Ddim + d0);
      #pragma unroll
      for (int e = 0; e < 4; ++e) {
        float x = (float)qv[e];
        ap[e] += ca * x;
        vp[e] += cv * x;
      }
    }
    bf16x4 pf, pa, pv;
    #pragma unroll
    for (int e = 0; e < 4; ++e) {
      pf[e] = (bf16_t)(0.5f * (ap[e] + vp[e]));
      pa[e] = (bf16_t)ap[e];
      pv[e] = (bf16_t)vp[e];
    }
    *(bf16x4*)(pooled + b * 3072 + d0)        = pf;
    *(bf16x4*)(pooled + b * 3072 + 1024 + d0) = pa;
    *(bf16x4*)(pooled + b * 3072 + 2048 + d0) = pv;
  }
}

// ---------------- LayerNorm + ReLU over F=512 (one wave per row) ----------------
__global__ __launch_bounds__(256) void k_ln(
    const float* __restrict__ Y,
    const float* __restrict__ fb, const float* __restrict__ fg, const float* __restrict__ fbe,
    const float* __restrict__ ab, const float* __restrict__ ag, const float* __restrict__ abe,
    const float* __restrict__ vb, const float* __restrict__ vg, const float* __restrict__ vbe,
    float* __restrict__ out) {
  int wave = threadIdx.x >> 6, lane = threadIdx.x & 63;
  long row = (long)blockIdx.x * 4 + wave;        // [0, 3*B)
  int head = (int)(row >> 11);
  const float* bb = (head == 0) ? fb : (head == 1) ? ab : vb;
  const float* gg = (head == 0) ? fg : (head == 1) ? ag : vg;
  const float* be = (head == 0) ? fbe : (head == 1) ? abe : vbe;
  const float* y = Y + row * Fdim + lane * 8;
  float v[8];
  float s = 0.f;
  #pragma unroll
  for (int k = 0; k < 8; ++k) { v[k] = y[k] + bb[lane * 8 + k]; s += v[k]; }
  #pragma unroll
  for (int m = 1; m < 64; m <<= 1) s += __shfl_xor(s, m);
  float mu = s * (1.f / Fdim);
  float vs = 0.f;
  #pragma unroll
  for (int k = 0; k < 8; ++k) { float t = v[k] - mu; vs += t * t; }
  #pragma unroll
  for (int m = 1; m < 64; m <<= 1) vs += __shfl_xor(vs, m);
  float inv = rsqrtf(vs * (1.f / Fdim) + 1e-5f);
  float* o = out + row * Fdim + lane * 8;
  #pragma unroll
  for (int k = 0; k < 8; ++k) {
    float t = (v[k] - mu) * inv * gg[lane * 8 + k] + be[lane * 8 + k];
    o[k] = fmaxf(t, 0.f);
  }
}

// ---------------- launch ----------------
extern "C" void kernel_launch(void* const* d_in, const int* in_sizes, int n_in,
                              void* d_out, int out_size, void* d_ws, size_t ws_size,
                              hipStream_t stream) {
  const float* q    = (const float*)d_in[0];
  const float* ipw  = (const float*)d_in[1];
  const float* ipb  = (const float*)d_in[2];
  const float* ow   = (const float*)d_in[3];
  const float* ob   = (const float*)d_in[4];
  const float* cw1  = (const float*)d_in[5];
  const float* cb1  = (const float*)d_in[6];
  const float* cw2  = (const float*)d_in[7];
  const float* cb2  = (const float*)d_in[8];
  const float* fusw = (const float*)d_in[9];
  const float* fusb = (const float*)d_in[10];
  const float* fusg = (const float*)d_in[11];
  const float* fusbe= (const float*)d_in[12];
  const float* paw  = (const float*)d_in[13];
  const float* pab  = (const float*)d_in[14];
  const float* pag  = (const float*)d_in[15];
  const float* pabe = (const float*)d_in[16];
  const float* pvw  = (const float*)d_in[17];
  const float* pvb  = (const float*)d_in[18];
  const float* pvg  = (const float*)d_in[19];
  const float* pvbe = (const float*)d_in[20];
  float* out = (float*)d_out;

  // workspace layout (bytes)
  const size_t o_q16   = 0;                    // 134217728
  const size_t o_w16   = 134217728;            // 6291456 (Wq,Wk,Wv)
  const size_t o_ow16  = 140509184;            // 2097152
  const size_t o_cls16 = 142606336;            // 33554432
  const size_t o_hw16  = 176160768;            // 3145728 (fus,pa,pv)
  const size_t o_Mt    = 179306496;            // 2097152
  const size_t o_Nt    = 181403648;            // 2097152
  const size_t o_G16   = 183500800;            // 134217728 (aliased later by S1,Y)
  const size_t o_pool  = 317718528;            // 12582912
  const size_t o_u     = 330301440;            // 4096
  const size_t o_wv    = 330305536;            // 4096
  const size_t o_bp    = 330309632;            // 4096
  const size_t o_c0    = 330313728;            // 256
  const size_t o_dsum  = 330313984;            // 262144
  const size_t o_daws  = 330576128;            // 262144
  const size_t total   = 330838272;
  if (ws_size < total) return;

  char* ws = (char*)d_ws;
  bf16_t* q16   = (bf16_t*)(ws + o_q16);
  bf16_t* w16   = (bf16_t*)(ws + o_w16);
  bf16_t* Wq16  = w16;
  bf16_t* Wk16  = w16 + 1048576;
  bf16_t* Wv16  = w16 + 2097152;
  bf16_t* ow16  = (bf16_t*)(ws + o_ow16);
  bf16_t* cls16 = (bf16_t*)(ws + o_cls16);
  bf16_t* hw16  = (bf16_t*)(ws + o_hw16);
  bf16_t* Mt    = (bf16_t*)(ws + o_Mt);
  bf16_t* Nt    = (bf16_t*)(ws + o_Nt);
  bf16_t* G16   = (bf16_t*)(ws + o_G16);
  bf16_t* S116  = (bf16_t*)(ws + o_G16);                 // alias (G16 dead by then)
  float*  Yf    = (float*)(ws + o_G16 + 12582912);       // alias
  bf16_t* pool16= (bf16_t*)(ws + o_pool);
  float*  uf    = (float*)(ws + o_u);
  float*  wvf   = (float*)(ws + o_wv);
  float*  bpf   = (float*)(ws + o_bp);
  float*  c0f   = (float*)(ws + o_c0);
  float*  dsum  = (float*)(ws + o_dsum);
  float*  daws  = (float*)(ws + o_daws);

  // 1) one fused convert for everything
  k_cvt_all<<<dim3(87552), dim3(256), 0, stream>>>(
      q, ipw, ow, cw1, fusw, paw, pvw, q16, w16, ow16, cls16, hw16);

  // 2) bias precompute
  k_bias_pre<<<dim3(137), dim3(256), 0, stream>>>(ipw, ipb, ow, ob, uf, wvf, bpf, c0f);

  // 3) M^T = Wk^T Wq
  k_gemm_bf16<1, 1><<<dim3(8, 8, 1), dim3(256), 0, stream>>>(
      Wk16, Ddim, 0, Wq16, Ddim, 0, Mt, Ddim, 0, nullptr, Ddim);

  // 4) N^T = Wo @ Wv
  k_gemm_bf16<0, 1><<<dim3(8, 8, 1), dim3(256), 0, stream>>>(
      ow16, Ddim, 0, Wv16, Ddim, 0, Nt, Ddim, 0, nullptr, Ddim);

  // 5) G = q16 @ M   (256x256 tile, BK=64, 8-phase counted-vmcnt schedule)
  k_gemm_big8<<<dim3(1024), dim3(512), 0, stream>>>(q16, Mt, G16);

  // 6) classifier
  hipMemsetAsync(dsum, 0, (size_t)Bdim * Sdim * sizeof(float), stream);
  k_gemm_cls<<<dim3(4, 16, 32), dim3(256), 0, stream>>>(q16, cls16, cb1, cw2, dsum);

  // 7) d -> softmaxes -> d_a,d_v
  k_finalize_d<<<dim3(256), dim3(256), 0, stream>>>(
      dsum, cb2, daws, out + 3145728, out + 3145728 + 32768);

  // 8) per-batch attention scores + pooling
  k_attn_pool<<<dim3(2048), dim3(256), 0, stream>>>(q16, G16, daws, uf, wvf, c0f, pool16);

  // 9) S1 = pooled @ N + b'
  k_gemm_bf16<0, 0><<<dim3(8, 48, 1), dim3(256), 0, stream>>>(
      pool16, Ddim, 0, Nt, Ddim, 0, S116, Ddim, 0, bpf, Ddim);

  // 10) heads: Y[z] = S1[:,z,:] @ headw[z]^T
  k_gemm_f32<<<dim3(4, 16, 3), dim3(256), 0, stream>>>(
      S116, 3L * Ddim, Ddim, hw16, Ddim, (long)Fdim * Ddim,
      Yf, Fdim, (long)Bdim * Fdim, Ddim);

  // 11) LN + ReLU -> out
  k_ln<<<dim3(1536), dim3(256), 0, stream>>>(
      Yf, fusb, fusg, fusbe, pab, pag, pabe, pvb, pvg, pvbe, out);
}